// Round 4
// baseline (213.703 us; speedup 1.0000x reference)
//
#include <hip/hip_runtime.h>
#include <hip/hip_bf16.h>

#define HIDDEN 4096
#define NHEADS 32
#define HDIM 128
#define CLEN 512
#define BATCH 32

// ---------------------------------------------------------------------------
// Projection: Y[b][o] = sum_k X[b][k] * W[o][k]   (X: [32][4096], W row-major)
// Register-blocked SGEMV, coalesced W streaming (unchanged from round 3:
// proj kernels measured near their streaming floor).
// ---------------------------------------------------------------------------
__device__ __forceinline__ void proj_body(const float* __restrict__ X,
                                          const float* __restrict__ W,
                                          float* __restrict__ Y,
                                          int rowblock) {
    const int t   = threadIdx.x;
    const int l   = t & 63;
    const int wid = t >> 6;                      // 0..7 -> batch quartet
    const int rowbase = rowblock * 8;
    const float* wp = W + (size_t)rowbase * HIDDEN + 4 * l;
    const float* xp = X + (size_t)(wid * 4) * HIDDEN + 4 * l;

    float v[32];
    #pragma unroll
    for (int j = 0; j < 32; ++j) v[j] = 0.f;

    #pragma unroll 2
    for (int kp = 0; kp < HIDDEN; kp += 256) {
        float4 wv[8], xv[4];
        #pragma unroll
        for (int r = 0; r < 8; ++r)
            wv[r] = *(const float4*)(wp + (size_t)r * HIDDEN + kp);
        #pragma unroll
        for (int b = 0; b < 4; ++b)
            xv[b] = *(const float4*)(xp + (size_t)b * HIDDEN + kp);
        #pragma unroll
        for (int r = 0; r < 8; ++r) {
            #pragma unroll
            for (int b = 0; b < 4; ++b) {
                v[r * 4 + b] += wv[r].x * xv[b].x + wv[r].y * xv[b].y +
                                wv[r].z * xv[b].z + wv[r].w * xv[b].w;
            }
        }
    }

    #pragma unroll
    for (int j = 0; j < 32; ++j) v[j] += __shfl_xor(v[j], 1);
    #pragma unroll
    for (int s = 1; s <= 5; ++s) {
        const int m = 1 << s;
        const int bit = (l >> s) & 1;
        #pragma unroll
        for (int i = 0; i < (32 >> s); ++i) {
            float t0 = __shfl_xor(v[2 * i], m);
            float t1 = __shfl_xor(v[2 * i + 1], m);
            v[i] = bit ? (v[2 * i + 1] + t1) : (v[2 * i] + t0);
        }
    }
    if (!(l & 1)) {
        const int j = l >> 1;
        const int r = j >> 2, b = j & 3;
        Y[(size_t)(wid * 4 + b) * HIDDEN + rowbase + r] = v[0];
    }
}

__global__ __launch_bounds__(512, 2) void proj_dual_kernel(const float* __restrict__ X,
                                                           const float* __restrict__ Wa,
                                                           const float* __restrict__ Wb,
                                                           float* __restrict__ Ya,
                                                           float* __restrict__ Yb) {
    const int bx = blockIdx.x;
    proj_body(X, (bx & 1) ? Wb : Wa, (bx & 1) ? Yb : Ya, bx >> 1);
}

__global__ __launch_bounds__(512, 2) void proj_out_kernel(const float* __restrict__ X,
                                                          const float* __restrict__ W,
                                                          float* __restrict__ Y) {
    proj_body(X, W, Y, blockIdx.x);
}

// ---------------------------------------------------------------------------
// Cache attention per (b,h): 512 threads = 8 waves, 64 keys per wave.
// Scores (shuffle-chain-free): per round, lane computes a float4 partial dot
// (coalesced), ONE shfl_xor(16) fold, writes 16 partials/key to LDS at
// stride 17 (conflict-free). 32 independent rounds, unroll 8 -> 8 loads in
// flight/wave. Reduce pass: thread t sums key t's 16 partials (stride-17,
// conflict-free). PV: unroll 8. Fuses + v_new (new-token softmax == 1).
// ---------------------------------------------------------------------------
#define PSTRIDE 17

__global__ __launch_bounds__(512, 4) void attn_kernel(const float* __restrict__ q,    // [32][4096]
                                                      const float* __restrict__ kc,   // [32][32][512][128]
                                                      const float* __restrict__ vc,
                                                      const float* __restrict__ vnew, // [32][4096]
                                                      float* __restrict__ attn_out) { // [32][4096]
    __shared__ float part_lds[CLEN * PSTRIDE];   // 34816 B
    __shared__ float sc[CLEN];
    __shared__ float red[16];
    __shared__ float part[8 * HDIM];
    const int t = threadIdx.x;
    const int w = t >> 6;
    const int l = t & 63;
    const int bh = blockIdx.x;
    const int b = bh >> 5, h = bh & 31;
    const float* K = kc + (size_t)bh * CLEN * HDIM;
    const float* V = vc + (size_t)bh * CLEN * HDIM;
    const float scale = 0.088388347648318447f;   // 1/sqrt(128)
    const int d0 = 4 * (l & 31);
    const int kh = l >> 5;                       // half-wave: key parity
    const size_t hoff = (size_t)b * HIDDEN + h * HDIM;
    float4 q4 = *(const float4*)(q + hoff + d0);

    // ---- scores: wave covers keys [w*64, w*64+64), 2 keys per round ----
    const int kbeg = w * 64;
    const bool wr = (l & 16) == 0;               // lanes 0-15, 32-47 write
    const int pj = l & 15;
    #pragma unroll 8
    for (int r = 0; r < 32; ++r) {
        const int k = kbeg + 2 * r + kh;
        float4 kv = *(const float4*)(K + (size_t)k * HDIM + d0);
        float p = q4.x * kv.x + q4.y * kv.y + q4.z * kv.z + q4.w * kv.w;
        p += __shfl_xor(p, 16);                  // fold to 16 partials/key
        if (wr) part_lds[k * PSTRIDE + pj] = p;
    }
    __syncthreads();

    // ---- reduce + softmax: thread t owns key t ----
    float s = 0.f;
    #pragma unroll
    for (int j = 0; j < 16; ++j) s += part_lds[t * PSTRIDE + j];
    s *= scale;
    float mx = s;
    #pragma unroll
    for (int m = 32; m; m >>= 1) mx = fmaxf(mx, __shfl_xor(mx, m));
    if (l == 0) red[w] = mx;
    __syncthreads();
    mx = fmaxf(fmaxf(fmaxf(red[0], red[1]), fmaxf(red[2], red[3])),
               fmaxf(fmaxf(red[4], red[5]), fmaxf(red[6], red[7])));
    float e = __expf(s - mx);
    sc[t] = e;
    float es = e;
    #pragma unroll
    for (int m = 32; m; m >>= 1) es += __shfl_xor(es, m);
    if (l == 0) red[8 + w] = es;
    __syncthreads();
    const float inv = 1.0f / (red[8] + red[9] + red[10] + red[11] +
                              red[12] + red[13] + red[14] + red[15]);

    // ---- PV: same key range, float4, 2 keys per wave-instr, deep unroll ----
    float4 acc = make_float4(0.f, 0.f, 0.f, 0.f);
    #pragma unroll 8
    for (int k = kbeg; k < kbeg + 64; k += 2) {
        float4 v4 = *(const float4*)(V + (size_t)(k + kh) * HDIM + d0);
        float p = sc[k + kh];
        acc.x += p * v4.x; acc.y += p * v4.y;
        acc.z += p * v4.z; acc.w += p * v4.w;
    }
    acc.x += __shfl_xor(acc.x, 32);
    acc.y += __shfl_xor(acc.y, 32);
    acc.z += __shfl_xor(acc.z, 32);
    acc.w += __shfl_xor(acc.w, 32);
    if (l < 32) *(float4*)(&part[w * HDIM + d0]) = acc;
    __syncthreads();
    if (t < HDIM) {
        float r = 0.f;
        #pragma unroll
        for (int ww = 0; ww < 8; ++ww) r += part[ww * HDIM + t];
        attn_out[hoff + t] = r * inv + vnew[hoff + t];
    }
}

extern "C" void kernel_launch(void* const* d_in, const int* in_sizes, int n_in,
                              void* d_out, int out_size, void* d_ws, size_t ws_size,
                              hipStream_t stream) {
    (void)in_sizes; (void)n_in; (void)out_size; (void)ws_size;
    const float* x  = (const float*)d_in[0];
    const float* kc = (const float*)d_in[1];
    const float* vc = (const float*)d_in[2];
    const float* wq = (const float*)d_in[3];
    // d_in[4] (wk) unused: softmax over a single new key is exactly 1.0
    const float* wv = (const float*)d_in[5];
    const float* wo = (const float*)d_in[6];
    float* out = (float*)d_out;

    float* q    = (float*)d_ws;                 // 32*4096 fp32
    float* vnew = q + BATCH * HIDDEN;           // 32*4096 fp32
    float* attn = vnew + BATCH * HIDDEN;        // 32*4096 fp32

    proj_dual_kernel<<<2 * (HIDDEN / 8), 512, 0, stream>>>(x, wq, wv, q, vnew);
    attn_kernel<<<BATCH * NHEADS, 512, 0, stream>>>(q, kc, vc, vnew, attn);
    proj_out_kernel<<<HIDDEN / 8, 512, 0, stream>>>(attn, wo, out);
}

// Round 5
// 198.722 us; speedup vs baseline: 1.0754x; 1.0754x over previous
//
#include <hip/hip_runtime.h>
#include <hip/hip_bf16.h>

#define HIDDEN 4096
#define NHEADS 32
#define HDIM 128
#define CLEN 512
#define BATCH 32

// ---------------------------------------------------------------------------
// Projection: Y[b][o] = sum_k X[b][k] * W[o][k]   (X: [32][4096], W row-major)
// Register-blocked SGEMV, coalesced W streaming (unchanged: measured near the
// weight-streaming floor in rounds 3/4).
// ---------------------------------------------------------------------------
__device__ __forceinline__ void proj_body(const float* __restrict__ X,
                                          const float* __restrict__ W,
                                          float* __restrict__ Y,
                                          int rowblock) {
    const int t   = threadIdx.x;
    const int l   = t & 63;
    const int wid = t >> 6;                      // 0..7 -> batch quartet
    const int rowbase = rowblock * 8;
    const float* wp = W + (size_t)rowbase * HIDDEN + 4 * l;
    const float* xp = X + (size_t)(wid * 4) * HIDDEN + 4 * l;

    float v[32];
    #pragma unroll
    for (int j = 0; j < 32; ++j) v[j] = 0.f;

    #pragma unroll 2
    for (int kp = 0; kp < HIDDEN; kp += 256) {
        float4 wv[8], xv[4];
        #pragma unroll
        for (int r = 0; r < 8; ++r)
            wv[r] = *(const float4*)(wp + (size_t)r * HIDDEN + kp);
        #pragma unroll
        for (int b = 0; b < 4; ++b)
            xv[b] = *(const float4*)(xp + (size_t)b * HIDDEN + kp);
        #pragma unroll
        for (int r = 0; r < 8; ++r) {
            #pragma unroll
            for (int b = 0; b < 4; ++b) {
                v[r * 4 + b] += wv[r].x * xv[b].x + wv[r].y * xv[b].y +
                                wv[r].z * xv[b].z + wv[r].w * xv[b].w;
            }
        }
    }

    #pragma unroll
    for (int j = 0; j < 32; ++j) v[j] += __shfl_xor(v[j], 1);
    #pragma unroll
    for (int s = 1; s <= 5; ++s) {
        const int m = 1 << s;
        const int bit = (l >> s) & 1;
        #pragma unroll
        for (int i = 0; i < (32 >> s); ++i) {
            float t0 = __shfl_xor(v[2 * i], m);
            float t1 = __shfl_xor(v[2 * i + 1], m);
            v[i] = bit ? (v[2 * i + 1] + t1) : (v[2 * i] + t0);
        }
    }
    if (!(l & 1)) {
        const int j = l >> 1;
        const int r = j >> 2, b = j & 3;
        Y[(size_t)(wid * 4 + b) * HIDDEN + rowbase + r] = v[0];
    }
}

__global__ __launch_bounds__(512, 2) void proj_dual_kernel(const float* __restrict__ X,
                                                           const float* __restrict__ Wa,
                                                           const float* __restrict__ Wb,
                                                           float* __restrict__ Ya,
                                                           float* __restrict__ Yb) {
    const int bx = blockIdx.x;
    proj_body(X, (bx & 1) ? Wb : Wa, (bx & 1) ? Yb : Ya, bx >> 1);
}

__global__ __launch_bounds__(512, 2) void proj_out_kernel(const float* __restrict__ X,
                                                          const float* __restrict__ W,
                                                          float* __restrict__ Y) {
    proj_body(X, W, Y, blockIdx.x);
}

// ---------------------------------------------------------------------------
// Attention, split-K flash style. Grid 2048: block = (bh, half), 256 threads
// (4 waves), ~3 KB LDS, launch_bounds(256,8) -> 8 blocks/CU co-resident,
// 32 waves/CU, zero tail. Each block covers 256 keys:
//   scores (5-step half-wave shuffle dot) -> local softmax (m, s) ->
//   unnormalized PV -> writes o_half[128], m, s to ws.
// Exact two-way merge done by combine_kernel.
// ---------------------------------------------------------------------------
#define KB 256   // keys per block

__global__ __launch_bounds__(256, 8) void attn_split_kernel(
        const float* __restrict__ q,     // [32][4096]
        const float* __restrict__ kc,    // [32][32][512][128]
        const float* __restrict__ vc,
        float* __restrict__ o_half,      // [2048][128]
        float* __restrict__ ms,          // [2048]
        float* __restrict__ ss) {        // [2048]
    __shared__ float sc[KB];
    __shared__ float red[8];
    __shared__ float part[4 * HDIM];
    const int t = threadIdx.x;
    const int w = t >> 6;                 // wave 0..3
    const int l = t & 63;
    const int bid = blockIdx.x;
    const int bh = bid >> 1;
    const int half = bid & 1;
    const int b = bh >> 5, h = bh & 31;
    const int kbase = half * KB;          // global key offset
    const float* K = kc + (size_t)bh * CLEN * HDIM + (size_t)kbase * HDIM;
    const float* V = vc + (size_t)bh * CLEN * HDIM + (size_t)kbase * HDIM;
    const float scale = 0.088388347648318447f;   // 1/sqrt(128)
    const int d0 = 4 * (l & 31);
    const int kh = l >> 5;                // half-wave key parity
    float4 q4 = *(const float4*)(q + (size_t)b * HIDDEN + h * HDIM + d0);

    // ---- scores: wave covers local keys [w*64, w*64+64), 2 per round ----
    const int kw = w * 64;
    #pragma unroll 8
    for (int r = 0; r < 32; ++r) {
        const int k = kw + 2 * r + kh;
        float4 kv = *(const float4*)(K + (size_t)k * HDIM + d0);
        float p = q4.x * kv.x + q4.y * kv.y + q4.z * kv.z + q4.w * kv.w;
        #pragma unroll
        for (int m = 16; m; m >>= 1) p += __shfl_xor(p, m);
        if ((l & 31) == 0) sc[k] = p * scale;
    }
    __syncthreads();

    // ---- local softmax over 256 keys: thread t owns local key t ----
    float s = sc[t];
    float mx = s;
    #pragma unroll
    for (int m = 32; m; m >>= 1) mx = fmaxf(mx, __shfl_xor(mx, m));
    if (l == 0) red[w] = mx;
    __syncthreads();
    mx = fmaxf(fmaxf(red[0], red[1]), fmaxf(red[2], red[3]));
    float e = __expf(s - mx);
    sc[t] = e;
    float es = e;
    #pragma unroll
    for (int m = 32; m; m >>= 1) es += __shfl_xor(es, m);
    if (l == 0) red[4 + w] = es;
    __syncthreads();
    if (t == 0) {
        ms[bid] = mx;
        ss[bid] = red[4] + red[5] + red[6] + red[7];
    }

    // ---- PV (unnormalized): 2 keys per wave-instr ----
    float4 acc = make_float4(0.f, 0.f, 0.f, 0.f);
    #pragma unroll 8
    for (int k = kw; k < kw + 64; k += 2) {
        float4 v4 = *(const float4*)(V + (size_t)(k + kh) * HDIM + d0);
        float p = sc[k + kh];
        acc.x += p * v4.x; acc.y += p * v4.y;
        acc.z += p * v4.z; acc.w += p * v4.w;
    }
    acc.x += __shfl_xor(acc.x, 32);
    acc.y += __shfl_xor(acc.y, 32);
    acc.z += __shfl_xor(acc.z, 32);
    acc.w += __shfl_xor(acc.w, 32);
    if (l < 32) *(float4*)(&part[w * HDIM + d0]) = acc;
    __syncthreads();
    if (t < HDIM) {
        float r = part[t] + part[HDIM + t] + part[2 * HDIM + t] + part[3 * HDIM + t];
        o_half[(size_t)bid * HDIM + t] = r;
    }
}

// ---------------------------------------------------------------------------
// Exact softmax merge of the two key-halves + v_new add.
// out[bh][d] = (o0*w0 + o1*w1)/(s0*w0 + s1*w1) + vnew,  w_h = exp(m_h - M).
// ---------------------------------------------------------------------------
__global__ __launch_bounds__(256) void combine_kernel(
        const float* __restrict__ o_half,
        const float* __restrict__ ms,
        const float* __restrict__ ss,
        const float* __restrict__ vnew,   // [32][4096]
        float* __restrict__ attn_out) {   // [32][4096]
    const int t = threadIdx.x;
    const int bh = blockIdx.x * 2 + (t >> 7);
    const int d = t & 127;
    const float m0 = ms[2 * bh], m1 = ms[2 * bh + 1];
    const float s0 = ss[2 * bh], s1 = ss[2 * bh + 1];
    const float M = fmaxf(m0, m1);
    const float w0 = __expf(m0 - M), w1 = __expf(m1 - M);
    const float inv = 1.0f / (s0 * w0 + s1 * w1);
    const float o0 = o_half[(size_t)(2 * bh) * HDIM + d];
    const float o1 = o_half[(size_t)(2 * bh + 1) * HDIM + d];
    const int b = bh >> 5, h = bh & 31;
    const size_t idx = (size_t)b * HIDDEN + h * HDIM + d;
    attn_out[idx] = (o0 * w0 + o1 * w1) * inv + vnew[idx];
}

extern "C" void kernel_launch(void* const* d_in, const int* in_sizes, int n_in,
                              void* d_out, int out_size, void* d_ws, size_t ws_size,
                              hipStream_t stream) {
    (void)in_sizes; (void)n_in; (void)out_size; (void)ws_size;
    const float* x  = (const float*)d_in[0];
    const float* kc = (const float*)d_in[1];
    const float* vc = (const float*)d_in[2];
    const float* wq = (const float*)d_in[3];
    // d_in[4] (wk) unused: softmax over a single new key is exactly 1.0
    const float* wv = (const float*)d_in[5];
    const float* wo = (const float*)d_in[6];
    float* out = (float*)d_out;

    float* q      = (float*)d_ws;                    // 131072 floats
    float* vnew   = q + BATCH * HIDDEN;              // 131072
    float* attn   = vnew + BATCH * HIDDEN;           // 131072
    float* o_half = attn + BATCH * HIDDEN;           // 2048*128 = 262144
    float* ms     = o_half + 2 * BATCH * NHEADS * HDIM;  // 2048
    float* ss     = ms + 2 * BATCH * NHEADS;             // 2048

    proj_dual_kernel<<<2 * (HIDDEN / 8), 512, 0, stream>>>(x, wq, wv, q, vnew);
    attn_split_kernel<<<2 * BATCH * NHEADS, 256, 0, stream>>>(q, kc, vc, o_half, ms, ss);
    combine_kernel<<<BATCH * NHEADS / 2, 256, 0, stream>>>(o_half, ms, ss, vnew, attn);
    proj_out_kernel<<<HIDDEN / 8, 512, 0, stream>>>(attn, wo, out);
}

// Round 6
// 185.891 us; speedup vs baseline: 1.1496x; 1.0690x over previous
//
#include <hip/hip_runtime.h>
#include <hip/hip_bf16.h>

#define HIDDEN 4096
#define NHEADS 32
#define HDIM 128
#define CLEN 512
#define BATCH 32
#define KB 256   // keys per attention block

typedef float f32x4 __attribute__((ext_vector_type(4)));

// ---------------------------------------------------------------------------
// 8-row / 512-thread projection body (out-proj): unchanged, measured near
// its weight-streaming floor (~13 us for 64 MB).
// ---------------------------------------------------------------------------
__device__ __forceinline__ void proj_body(const float* __restrict__ X,
                                          const float* __restrict__ W,
                                          float* __restrict__ Y,
                                          int rowblock) {
    const int t   = threadIdx.x;
    const int l   = t & 63;
    const int wid = t >> 6;                      // 0..7 -> batch quartet
    const int rowbase = rowblock * 8;
    const float* wp = W + (size_t)rowbase * HIDDEN + 4 * l;
    const float* xp = X + (size_t)(wid * 4) * HIDDEN + 4 * l;

    float v[32];
    #pragma unroll
    for (int j = 0; j < 32; ++j) v[j] = 0.f;

    #pragma unroll 2
    for (int kp = 0; kp < HIDDEN; kp += 256) {
        float4 wv[8], xv[4];
        #pragma unroll
        for (int r = 0; r < 8; ++r)
            wv[r] = *(const float4*)(wp + (size_t)r * HIDDEN + kp);
        #pragma unroll
        for (int b = 0; b < 4; ++b)
            xv[b] = *(const float4*)(xp + (size_t)b * HIDDEN + kp);
        #pragma unroll
        for (int r = 0; r < 8; ++r) {
            #pragma unroll
            for (int b = 0; b < 4; ++b) {
                v[r * 4 + b] += wv[r].x * xv[b].x + wv[r].y * xv[b].y +
                                wv[r].z * xv[b].z + wv[r].w * xv[b].w;
            }
        }
    }

    #pragma unroll
    for (int j = 0; j < 32; ++j) v[j] += __shfl_xor(v[j], 1);
    #pragma unroll
    for (int s = 1; s <= 5; ++s) {
        const int m = 1 << s;
        const int bit = (l >> s) & 1;
        #pragma unroll
        for (int i = 0; i < (32 >> s); ++i) {
            float t0 = __shfl_xor(v[2 * i], m);
            float t1 = __shfl_xor(v[2 * i + 1], m);
            v[i] = bit ? (v[2 * i + 1] + t1) : (v[2 * i] + t0);
        }
    }
    if (!(l & 1)) {
        const int j = l >> 1;
        const int r = j >> 2, b = j & 3;
        Y[(size_t)(wid * 4 + b) * HIDDEN + rowbase + r] = v[0];
    }
}

__global__ __launch_bounds__(512, 2) void proj_out_kernel(const float* __restrict__ X,
                                                          const float* __restrict__ W,
                                                          float* __restrict__ Y) {
    proj_body(X, W, Y, blockIdx.x);
}

// ---------------------------------------------------------------------------
// 4-row / 256-thread projection body: wave wid handles batch octet
// (wid*8..wid*8+7) x 4 W-rows. Same coalesced W streaming + butterfly.
// ---------------------------------------------------------------------------
__device__ __forceinline__ void proj4_body(const float* __restrict__ X,
                                           const float* __restrict__ W,
                                           float* __restrict__ Y,
                                           int rowblock) {
    const int t   = threadIdx.x;
    const int l   = t & 63;
    const int wid = t >> 6;                      // 0..3 -> batch octet
    const int rowbase = rowblock * 4;
    const float* wp = W + (size_t)rowbase * HIDDEN + 4 * l;
    const float* xp = X + (size_t)(wid * 8) * HIDDEN + 4 * l;

    float v[32];
    #pragma unroll
    for (int j = 0; j < 32; ++j) v[j] = 0.f;

    #pragma unroll 2
    for (int kp = 0; kp < HIDDEN; kp += 256) {
        float4 wv[4], xv[8];
        #pragma unroll
        for (int r = 0; r < 4; ++r)
            wv[r] = *(const float4*)(wp + (size_t)r * HIDDEN + kp);
        #pragma unroll
        for (int b = 0; b < 8; ++b)
            xv[b] = *(const float4*)(xp + (size_t)b * HIDDEN + kp);
        #pragma unroll
        for (int r = 0; r < 4; ++r) {
            #pragma unroll
            for (int b = 0; b < 8; ++b) {
                v[r * 8 + b] += wv[r].x * xv[b].x + wv[r].y * xv[b].y +
                                wv[r].z * xv[b].z + wv[r].w * xv[b].w;
            }
        }
    }

    #pragma unroll
    for (int j = 0; j < 32; ++j) v[j] += __shfl_xor(v[j], 1);
    #pragma unroll
    for (int s = 1; s <= 5; ++s) {
        const int m = 1 << s;
        const int bit = (l >> s) & 1;
        #pragma unroll
        for (int i = 0; i < (32 >> s); ++i) {
            float t0 = __shfl_xor(v[2 * i], m);
            float t1 = __shfl_xor(v[2 * i + 1], m);
            v[i] = bit ? (v[2 * i + 1] + t1) : (v[2 * i] + t0);
        }
    }
    if (!(l & 1)) {
        const int j = l >> 1;                    // 0..31
        const int r = j >> 3, b = j & 7;
        Y[(size_t)(wid * 8 + b) * HIDDEN + rowbase + r] = v[0];
    }
}

__global__ __launch_bounds__(256) void proj_q_kernel(const float* __restrict__ X,
                                                     const float* __restrict__ W,
                                                     float* __restrict__ Y) {
    proj4_body(X, W, Y, blockIdx.x);
}

// ---------------------------------------------------------------------------
// Attention half-block body (256 keys), with:
//  * per-block key-visit STAGGER (rotate by even offset, decorrelates the
//    2048 concurrent 256KB-strided streams' low address bits)
//  * NON-TEMPORAL K/V loads (read-once data; keep it out of L1)
// Math identical to round 5 (exact flash-style half-softmax).
// ---------------------------------------------------------------------------
__device__ __forceinline__ void attn_body(const float* __restrict__ q,
                                          const float* __restrict__ kc,
                                          const float* __restrict__ vc,
                                          float* __restrict__ o_half,
                                          float* __restrict__ ms,
                                          float* __restrict__ ss,
                                          int bid) {
    __shared__ float sc[KB];
    __shared__ float red[8];
    __shared__ float part[4 * HDIM];
    const int t = threadIdx.x;
    const int w = t >> 6;                 // wave 0..3
    const int l = t & 63;
    const int bh = bid >> 1;
    const int half = bid & 1;
    const int b = bh >> 5, h = bh & 31;
    const float* K = kc + (size_t)bh * CLEN * HDIM + (size_t)(half * KB) * HDIM;
    const float* V = vc + (size_t)bh * CLEN * HDIM + (size_t)(half * KB) * HDIM;
    const float scale = 0.088388347648318447f;   // 1/sqrt(128)
    const int d0 = 4 * (l & 31);
    const int kh = l >> 5;                // half-wave key parity
    const int start = ((bid * 37) & 127) * 2;    // even stagger in [0,254]
    float4 q4 = *(const float4*)(q + (size_t)b * HIDDEN + h * HDIM + d0);

    // ---- scores: wave covers local keys [w*64, w*64+64) rotated by start ----
    const int kw = w * 64;
    #pragma unroll 8
    for (int r = 0; r < 32; ++r) {
        const int k = (((kw + 2 * r) + start) & (KB - 1)) + kh;
        f32x4 kv = __builtin_nontemporal_load((const f32x4*)(K + (size_t)k * HDIM + d0));
        float p = q4.x * kv.x + q4.y * kv.y + q4.z * kv.z + q4.w * kv.w;
        #pragma unroll
        for (int m = 16; m; m >>= 1) p += __shfl_xor(p, m);
        if ((l & 31) == 0) sc[k] = p * scale;
    }
    __syncthreads();

    // ---- local softmax over 256 keys: thread t owns local key t ----
    float s = sc[t];
    float mx = s;
    #pragma unroll
    for (int m = 32; m; m >>= 1) mx = fmaxf(mx, __shfl_xor(mx, m));
    if (l == 0) red[w] = mx;
    __syncthreads();
    mx = fmaxf(fmaxf(red[0], red[1]), fmaxf(red[2], red[3]));
    float e = __expf(s - mx);
    sc[t] = e;
    float es = e;
    #pragma unroll
    for (int m = 32; m; m >>= 1) es += __shfl_xor(es, m);
    if (l == 0) red[4 + w] = es;
    __syncthreads();
    if (t == 0) {
        ms[bid] = mx;
        ss[bid] = red[4] + red[5] + red[6] + red[7];
    }

    // ---- PV (unnormalized), same rotation ----
    float4 acc = make_float4(0.f, 0.f, 0.f, 0.f);
    #pragma unroll 8
    for (int kk = 0; kk < 64; kk += 2) {
        const int k = (((kw + kk) + start) & (KB - 1)) + kh;
        f32x4 v4 = __builtin_nontemporal_load((const f32x4*)(V + (size_t)k * HDIM + d0));
        float p = sc[k];
        acc.x += p * v4.x; acc.y += p * v4.y;
        acc.z += p * v4.z; acc.w += p * v4.w;
    }
    acc.x += __shfl_xor(acc.x, 32);
    acc.y += __shfl_xor(acc.y, 32);
    acc.z += __shfl_xor(acc.z, 32);
    acc.w += __shfl_xor(acc.w, 32);
    if (l < 32) *(float4*)(&part[w * HDIM + d0]) = acc;
    __syncthreads();
    if (t < HDIM) {
        float r = part[t] + part[HDIM + t] + part[2 * HDIM + t] + part[3 * HDIM + t];
        o_half[(size_t)bid * HDIM + t] = r;
    }
}

// ---------------------------------------------------------------------------
// Fused dispatch: 3072 blocks. bid%3==2 -> v-projection chunk (1024 blocks,
// 4 rows each); else attention half-block (2048). Interleaving lets proj_v's
// pure W-stream ride in attention's bandwidth slack.
// ---------------------------------------------------------------------------
__global__ __launch_bounds__(256) void attn_projv_kernel(
        const float* __restrict__ q, const float* __restrict__ kc,
        const float* __restrict__ vc, const float* __restrict__ x,
        const float* __restrict__ wv_m, float* __restrict__ vnew,
        float* __restrict__ o_half, float* __restrict__ ms,
        float* __restrict__ ss) {
    const int bid = blockIdx.x;
    const int sel = bid % 3;
    if (sel == 2) {
        proj4_body(x, wv_m, vnew, bid / 3);
        return;
    }
    attn_body(q, kc, vc, o_half, ms, ss, (bid / 3) * 2 + sel);
}

// ---------------------------------------------------------------------------
// Exact softmax merge of the two key-halves + v_new add.
// ---------------------------------------------------------------------------
__global__ __launch_bounds__(256) void combine_kernel(
        const float* __restrict__ o_half,
        const float* __restrict__ ms,
        const float* __restrict__ ss,
        const float* __restrict__ vnew,   // [32][4096]
        float* __restrict__ attn_out) {   // [32][4096]
    const int t = threadIdx.x;
    const int bh = blockIdx.x * 2 + (t >> 7);
    const int d = t & 127;
    const float m0 = ms[2 * bh], m1 = ms[2 * bh + 1];
    const float s0 = ss[2 * bh], s1 = ss[2 * bh + 1];
    const float M = fmaxf(m0, m1);
    const float w0 = __expf(m0 - M), w1 = __expf(m1 - M);
    const float inv = 1.0f / (s0 * w0 + s1 * w1);
    const float o0 = o_half[(size_t)(2 * bh) * HDIM + d];
    const float o1 = o_half[(size_t)(2 * bh + 1) * HDIM + d];
    const int b = bh >> 5, h = bh & 31;
    const size_t idx = (size_t)b * HIDDEN + h * HDIM + d;
    attn_out[idx] = (o0 * w0 + o1 * w1) * inv + vnew[idx];
}

extern "C" void kernel_launch(void* const* d_in, const int* in_sizes, int n_in,
                              void* d_out, int out_size, void* d_ws, size_t ws_size,
                              hipStream_t stream) {
    (void)in_sizes; (void)n_in; (void)out_size; (void)ws_size;
    const float* x  = (const float*)d_in[0];
    const float* kc = (const float*)d_in[1];
    const float* vc = (const float*)d_in[2];
    const float* wq = (const float*)d_in[3];
    // d_in[4] (wk) unused: softmax over a single new key is exactly 1.0
    const float* wv = (const float*)d_in[5];
    const float* wo = (const float*)d_in[6];
    float* out = (float*)d_out;

    float* q      = (float*)d_ws;                        // 131072 floats
    float* vnew   = q + BATCH * HIDDEN;                  // 131072
    float* attn   = vnew + BATCH * HIDDEN;               // 131072
    float* o_half = attn + BATCH * HIDDEN;               // 2048*128
    float* ms     = o_half + 2 * BATCH * NHEADS * HDIM;  // 2048
    float* ss     = ms + 2 * BATCH * NHEADS;             // 2048

    proj_q_kernel<<<HIDDEN / 4, 256, 0, stream>>>(x, wq, q);
    attn_projv_kernel<<<3072, 256, 0, stream>>>(q, kc, vc, x, wv, vnew,
                                                o_half, ms, ss);
    combine_kernel<<<BATCH * NHEADS / 2, 256, 0, stream>>>(o_half, ms, ss, vnew, attn);
    proj_out_kernel<<<HIDDEN / 8, 512, 0, stream>>>(attn, wo, out);
}

// Round 7
// 185.257 us; speedup vs baseline: 1.1536x; 1.0034x over previous
//
#include <hip/hip_runtime.h>
#include <hip/hip_bf16.h>

#define HIDDEN 4096
#define NHEADS 32
#define HDIM 128
#define CLEN 512
#define BATCH 32
#define KB 256   // keys per attention block (4 waves x 64 keys)

typedef float f32x4 __attribute__((ext_vector_type(4)));

// ---------------------------------------------------------------------------
// 8-row / 512-thread projection body (out-proj): measured near the
// weight-streaming floor (~13 us for 64 MB).
// ---------------------------------------------------------------------------
__device__ __forceinline__ void proj_body(const float* __restrict__ X,
                                          const float* __restrict__ W,
                                          float* __restrict__ Y,
                                          int rowblock) {
    const int t   = threadIdx.x;
    const int l   = t & 63;
    const int wid = t >> 6;                      // 0..7 -> batch quartet
    const int rowbase = rowblock * 8;
    const float* wp = W + (size_t)rowbase * HIDDEN + 4 * l;
    const float* xp = X + (size_t)(wid * 4) * HIDDEN + 4 * l;

    float v[32];
    #pragma unroll
    for (int j = 0; j < 32; ++j) v[j] = 0.f;

    #pragma unroll 2
    for (int kp = 0; kp < HIDDEN; kp += 256) {
        float4 wv[8], xv[4];
        #pragma unroll
        for (int r = 0; r < 8; ++r)
            wv[r] = *(const float4*)(wp + (size_t)r * HIDDEN + kp);
        #pragma unroll
        for (int b = 0; b < 4; ++b)
            xv[b] = *(const float4*)(xp + (size_t)b * HIDDEN + kp);
        #pragma unroll
        for (int r = 0; r < 8; ++r) {
            #pragma unroll
            for (int b = 0; b < 4; ++b) {
                v[r * 4 + b] += wv[r].x * xv[b].x + wv[r].y * xv[b].y +
                                wv[r].z * xv[b].z + wv[r].w * xv[b].w;
            }
        }
    }

    #pragma unroll
    for (int j = 0; j < 32; ++j) v[j] += __shfl_xor(v[j], 1);
    #pragma unroll
    for (int s = 1; s <= 5; ++s) {
        const int m = 1 << s;
        const int bit = (l >> s) & 1;
        #pragma unroll
        for (int i = 0; i < (32 >> s); ++i) {
            float t0 = __shfl_xor(v[2 * i], m);
            float t1 = __shfl_xor(v[2 * i + 1], m);
            v[i] = bit ? (v[2 * i + 1] + t1) : (v[2 * i] + t0);
        }
    }
    if (!(l & 1)) {
        const int j = l >> 1;
        const int r = j >> 2, b = j & 3;
        Y[(size_t)(wid * 4 + b) * HIDDEN + rowbase + r] = v[0];
    }
}

__global__ __launch_bounds__(512, 2) void proj_out_kernel(const float* __restrict__ X,
                                                          const float* __restrict__ W,
                                                          float* __restrict__ Y) {
    proj_body(X, W, Y, blockIdx.x);
}

// ---------------------------------------------------------------------------
// 4-row / 256-thread projection body (q-proj standalone, v-proj fused).
// ---------------------------------------------------------------------------
__device__ __forceinline__ void proj4_body(const float* __restrict__ X,
                                           const float* __restrict__ W,
                                           float* __restrict__ Y,
                                           int rowblock) {
    const int t   = threadIdx.x;
    const int l   = t & 63;
    const int wid = t >> 6;                      // 0..3 -> batch octet
    const int rowbase = rowblock * 4;
    const float* wp = W + (size_t)rowbase * HIDDEN + 4 * l;
    const float* xp = X + (size_t)(wid * 8) * HIDDEN + 4 * l;

    float v[32];
    #pragma unroll
    for (int j = 0; j < 32; ++j) v[j] = 0.f;

    #pragma unroll 2
    for (int kp = 0; kp < HIDDEN; kp += 256) {
        float4 wv[4], xv[8];
        #pragma unroll
        for (int r = 0; r < 4; ++r)
            wv[r] = *(const float4*)(wp + (size_t)r * HIDDEN + kp);
        #pragma unroll
        for (int b = 0; b < 8; ++b)
            xv[b] = *(const float4*)(xp + (size_t)b * HIDDEN + kp);
        #pragma unroll
        for (int r = 0; r < 4; ++r) {
            #pragma unroll
            for (int b = 0; b < 8; ++b) {
                v[r * 8 + b] += wv[r].x * xv[b].x + wv[r].y * xv[b].y +
                                wv[r].z * xv[b].z + wv[r].w * xv[b].w;
            }
        }
    }

    #pragma unroll
    for (int j = 0; j < 32; ++j) v[j] += __shfl_xor(v[j], 1);
    #pragma unroll
    for (int s = 1; s <= 5; ++s) {
        const int m = 1 << s;
        const int bit = (l >> s) & 1;
        #pragma unroll
        for (int i = 0; i < (32 >> s); ++i) {
            float t0 = __shfl_xor(v[2 * i], m);
            float t1 = __shfl_xor(v[2 * i + 1], m);
            v[i] = bit ? (v[2 * i + 1] + t1) : (v[2 * i] + t0);
        }
    }
    if (!(l & 1)) {
        const int j = l >> 1;                    // 0..31
        const int r = j >> 3, b = j & 7;
        Y[(size_t)(wid * 8 + b) * HIDDEN + rowbase + r] = v[0];
    }
}

__global__ __launch_bounds__(256) void proj_q_kernel(const float* __restrict__ X,
                                                     const float* __restrict__ W,
                                                     float* __restrict__ Y) {
    proj4_body(X, W, Y, blockIdx.x);
}

// ---------------------------------------------------------------------------
// Attention: fully wave-local online-softmax flash. ZERO LDS, ZERO barriers.
// Each wave owns 64 keys: per round (2 keys via half-wave split) it loads a
// K row pair, butterfly-reduces the score so every lane of each half holds
// its key's score, does the online (m,s,acc) update, loads the V row pair
// and accumulates. K/V form one interleaved monotonic stream per wave;
// unroll 4 keeps ~4 KB in flight. Per-wave partials (8 per bh) merged
// exactly in combine_kernel.
// ---------------------------------------------------------------------------
__device__ __forceinline__ void attn_body(const float* __restrict__ q,
                                          const float* __restrict__ kc,
                                          const float* __restrict__ vc,
                                          float* __restrict__ o_part,   // [8192][128]
                                          float* __restrict__ ms,       // [8192]
                                          float* __restrict__ ss,       // [8192]
                                          int bid) {
    const int t = threadIdx.x;
    const int w = t >> 6;                 // wave 0..3
    const int l = t & 63;
    const int bh = bid >> 1;
    const int half = bid & 1;
    const int b = bh >> 5, h = bh & 31;
    const float* K = kc + (size_t)bh * CLEN * HDIM + (size_t)(half * KB + w * 64) * HDIM;
    const float* V = vc + (size_t)bh * CLEN * HDIM + (size_t)(half * KB + w * 64) * HDIM;
    const float scale = 0.088388347648318447f;   // 1/sqrt(128)
    const int d0 = 4 * (l & 31);
    const int kh = l >> 5;                // half-wave key parity
    const int rot = (bid & 31) * 2;       // even stagger within the 64 keys
    f32x4 q4 = *(const f32x4*)(q + (size_t)b * HIDDEN + h * HDIM + d0);

    float mloc = -INFINITY, sloc = 0.f;
    f32x4 acc = {0.f, 0.f, 0.f, 0.f};

    #pragma unroll 4
    for (int r = 0; r < 32; ++r) {
        const int k = ((2 * r + rot) & 63) + kh;
        f32x4 kv = __builtin_nontemporal_load((const f32x4*)(K + (size_t)k * HDIM + d0));
        float p = q4.x * kv.x + q4.y * kv.y + q4.z * kv.z + q4.w * kv.w;
        #pragma unroll
        for (int m = 16; m; m >>= 1) p += __shfl_xor(p, m);  // all 32 lanes get sum
        p *= scale;
        f32x4 vv = __builtin_nontemporal_load((const f32x4*)(V + (size_t)k * HDIM + d0));
        const float mn = fmaxf(mloc, p);
        const float c = __expf(mloc - mn);   // 0 on first round (mloc=-inf)
        const float e = __expf(p - mn);
        sloc = sloc * c + e;
        acc = acc * c + vv * e;
        mloc = mn;
    }

    // ---- merge the two half-wave streams (keys even vs odd) ----
    const float mo = __shfl_xor(mloc, 32);
    const float M = fmaxf(mloc, mo);
    const float wsc = __expf(mloc - M);
    float sw = sloc * wsc;
    sw += __shfl_xor(sw, 32);
    acc *= wsc;
    acc.x += __shfl_xor(acc.x, 32);
    acc.y += __shfl_xor(acc.y, 32);
    acc.z += __shfl_xor(acc.z, 32);
    acc.w += __shfl_xor(acc.w, 32);

    const int pid = bh * 8 + half * 4 + w;
    if (l < 32) *(f32x4*)(o_part + (size_t)pid * HDIM + d0) = acc;
    if (l == 0) { ms[pid] = M; ss[pid] = sw; }
}

// ---------------------------------------------------------------------------
// Fused dispatch: 3072 blocks. bid%3==2 -> v-projection chunk (1024 blocks);
// else attention half-block (2048).
// ---------------------------------------------------------------------------
__global__ __launch_bounds__(256, 4) void attn_projv_kernel(
        const float* __restrict__ q, const float* __restrict__ kc,
        const float* __restrict__ vc, const float* __restrict__ x,
        const float* __restrict__ wv_m, float* __restrict__ vnew,
        float* __restrict__ o_part, float* __restrict__ ms,
        float* __restrict__ ss) {
    const int bid = blockIdx.x;
    const int sel = bid % 3;
    if (sel == 2) {
        proj4_body(x, wv_m, vnew, bid / 3);
        return;
    }
    attn_body(q, kc, vc, o_part, ms, ss, (bid / 3) * 2 + sel);
}

// ---------------------------------------------------------------------------
// Exact 8-way softmax merge + v_new add.
// out[bh][d] = sum_j o_j[d] w_j / sum_j s_j w_j + vnew,  w_j = exp(m_j - M).
// ---------------------------------------------------------------------------
__global__ __launch_bounds__(256) void combine_kernel(
        const float* __restrict__ o_part,
        const float* __restrict__ ms,
        const float* __restrict__ ss,
        const float* __restrict__ vnew,   // [32][4096]
        float* __restrict__ attn_out) {   // [32][4096]
    const int t = threadIdx.x;
    const int bh = blockIdx.x * 2 + (t >> 7);
    const int d = t & 127;
    float m[8];
    #pragma unroll
    for (int j = 0; j < 8; ++j) m[j] = ms[bh * 8 + j];
    float M = m[0];
    #pragma unroll
    for (int j = 1; j < 8; ++j) M = fmaxf(M, m[j]);
    float ssum = 0.f, o = 0.f;
    #pragma unroll
    for (int j = 0; j < 8; ++j) {
        const float wj = __expf(m[j] - M);
        ssum += ss[bh * 8 + j] * wj;
        o += o_part[(size_t)(bh * 8 + j) * HDIM + d] * wj;
    }
    const int b = bh >> 5, h = bh & 31;
    const size_t idx = (size_t)b * HIDDEN + h * HDIM + d;
    attn_out[idx] = o / ssum + vnew[idx];
}

extern "C" void kernel_launch(void* const* d_in, const int* in_sizes, int n_in,
                              void* d_out, int out_size, void* d_ws, size_t ws_size,
                              hipStream_t stream) {
    (void)in_sizes; (void)n_in; (void)out_size; (void)ws_size;
    const float* x  = (const float*)d_in[0];
    const float* kc = (const float*)d_in[1];
    const float* vc = (const float*)d_in[2];
    const float* wq = (const float*)d_in[3];
    // d_in[4] (wk) unused: softmax over a single new key is exactly 1.0
    const float* wv = (const float*)d_in[5];
    const float* wo = (const float*)d_in[6];
    float* out = (float*)d_out;

    float* q      = (float*)d_ws;                        // 131072 floats
    float* vnew   = q + BATCH * HIDDEN;                  // 131072
    float* attn   = vnew + BATCH * HIDDEN;               // 131072
    float* o_part = attn + BATCH * HIDDEN;               // 8192*128
    float* ms     = o_part + 8 * BATCH * NHEADS * HDIM;  // 8192
    float* ss     = ms + 8 * BATCH * NHEADS;             // 8192

    proj_q_kernel<<<HIDDEN / 4, 256, 0, stream>>>(x, wq, q);
    attn_projv_kernel<<<3072, 256, 0, stream>>>(q, kc, vc, x, wv, vnew,
                                                o_part, ms, ss);
    combine_kernel<<<BATCH * NHEADS / 2, 256, 0, stream>>>(o_part, ms, ss, vnew, attn);
    proj_out_kernel<<<HIDDEN / 8, 512, 0, stream>>>(attn, wo, out);
}